// Round 6
// baseline (26.094 us; speedup 1.0000x reference)
//
#include <hip/hip_runtime.h>
#include <math.h>

// Problem constants
constexpr int Bb = 8, Cc = 16, Hh = 96, Ww = 96;
constexpr int Ho = 94, Wo = 94;          // VALID 3x3
constexpr int NC = 4;                    // n_convs
constexpr int PLANE = Ho * Wo;           // 8836

// Tiling: 16x16 outputs/block, 256 threads = 4 waves, each wave does 4 rows via MFMA
constexpr int TX = 16, TY = 16;
constexpr int IX = 18, IY = 18;          // input/feature tile
constexpr int NXT = 6, NYT = 6;
constexpr int FS = 12;                   // bf16 per record: b0..b7, silu, 0,0,0
constexpr int ROWU = IX * FS;            // 216 ushorts per feature row
// K layout: k = rec*12 + coeff, rec = dy*3+dx (0..8), K=108 padded to 128.

typedef __attribute__((ext_vector_type(4))) float f32x4;
typedef __attribute__((ext_vector_type(8))) short bf16x8;

__device__ __forceinline__ unsigned short f2bf(float f) {
    union { float f; unsigned u; } a; a.f = f;
    unsigned r = a.u + 0x7fffu + ((a.u >> 16) & 1u);   // RNE
    return (unsigned short)(r >> 16);
}
__device__ __forceinline__ unsigned pk2(float a, float b) {
    return (unsigned)f2bf(a) | ((unsigned)f2bf(b) << 16);
}
__device__ __forceinline__ bf16x8 mkfrag(unsigned a0, unsigned a1, unsigned a2, unsigned a3) {
    union { unsigned u[4]; bf16x8 v; } t;
    t.u[0] = a0; t.u[1] = a1; t.u[2] = a2; t.u[3] = a3;
    return t.v;
}
__device__ __forceinline__ int recIdx(int i, int r) {    // ushort index of record (dy,dx)=(i/3,i%3)
    return ((i / 3) * IX + r + (i % 3)) * FS;
}

struct F4 { float v0, v1, v2, v3; } __attribute__((packed, aligned(4)));

#define LD2(p, off) (*reinterpret_cast<const uint2*>((const char*)(p) + (off)))

__global__ __launch_bounds__(256)
void kan_conv_kernel(const float* __restrict__ x,
                     const float* __restrict__ base_w,        // (4,9)
                     const float* __restrict__ spline_w,      // (4,9,8)
                     const float* __restrict__ spline_scaler, // (4,9)
                     const float* __restrict__ grid,          // (12)
                     float* __restrict__ out)                 // (8,64,94,94)
{
    __shared__ unsigned short feat[IY * IX * FS];  // 7776 B, bf16 records
    __shared__ unsigned short Bw[16 * 128];        // 4096 B, merged weights [cv][k] bf16

    const int tid = threadIdx.x;
    int blk = blockIdx.x;
    const int xt = blk % NXT; blk /= NXT;
    const int yt = blk % NYT; blk /= NYT;
    const int c  = blk % Cc;
    const int b  = blk / Cc;
    const int ox0 = xt * TX, oy0 = yt * TY;

    // ---------- Phase 0: merged-weight B matrix -> LDS (bf16, zero-padded to 16x128) ----------
    {
        const int cv = tid >> 4;          // 0..15 (only 0..3 nonzero)
        const int k0 = (tid & 15) * 8;    // 8 consecutive k per thread
        unsigned d0 = 0, d1 = 0, d2 = 0, d3 = 0;
        if (cv < NC) {
            float w0=0,w1=0,w2=0,w3=0,w4=0,w5=0,w6=0,w7=0;
#pragma unroll
            for (int e = 0; e < 8; ++e) {
                const int k = k0 + e;
                float val = 0.f;
                if (k < 108) {
                    const int i  = k / 12;
                    const int cc = k - 12 * i;
                    const int wi = cv * 9 + i;
                    if (cc < 8)       val = spline_scaler[wi] * spline_w[wi * 8 + cc];
                    else if (cc == 8) val = base_w[wi];
                }
                if      (e == 0) w0 = val; else if (e == 1) w1 = val;
                else if (e == 2) w2 = val; else if (e == 3) w3 = val;
                else if (e == 4) w4 = val; else if (e == 5) w5 = val;
                else if (e == 6) w6 = val; else              w7 = val;
            }
            d0 = pk2(w0, w1); d1 = pk2(w2, w3); d2 = pk2(w4, w5); d3 = pk2(w6, w7);
        }
        *reinterpret_cast<uint4*>(&Bw[cv * 128 + k0]) = make_uint4(d0, d1, d2, d3);
    }

    // ---------- Phase 1: per-pixel features -> bf16 records in LDS ----------
    const float g0   = grid[0];
    const float invh = 1.0f / (grid[1] - g0);
    const float* xplane = x + (size_t)(b * Cc + c) * Hh * Ww;

    for (int p = tid; p < IX * IY; p += 256) {
        const int py = p / IX, px = p % IX;
        const int gy = oy0 + py, gx = ox0 + px;
        const float v = (gy < Hh && gx < Ww) ? xplane[gy * Ww + gx] : 0.0f;

        const float sl = v / (1.0f + __expf(-v));   // silu

        const float u = (v - g0) * invh;
        int j = (int)u;
        if (!(u >= 0.0f && u < 11.0f)) j = -100;
        const float t  = u - (float)j;
        const float t2 = t * t, t3 = t2 * t;
        const float omt = 1.0f - t;
        const float B0 = (1.0f / 6.0f) * omt * omt * omt;
        const float B1 = (1.0f / 6.0f) * (3.0f * t3 - 6.0f * t2 + 4.0f);
        const float B2 = (1.0f / 6.0f) * (-3.0f * t3 + 3.0f * t2 + 3.0f * t + 1.0f);
        const float B3 = (1.0f / 6.0f) * t3;

        float bb[8];
#pragma unroll
        for (int k = 0; k < 8; ++k) {
            float r = 0.0f;
            r = (j == k + 3) ? B0 : r;
            r = (j == k + 2) ? B1 : r;
            r = (j == k + 1) ? B2 : r;
            r = (j == k    ) ? B3 : r;
            bb[k] = r;
        }

        unsigned short* fp = &feat[p * FS];
        *reinterpret_cast<uint2*>(fp + 0) = make_uint2(pk2(bb[0], bb[1]), pk2(bb[2], bb[3]));
        *reinterpret_cast<uint2*>(fp + 4) = make_uint2(pk2(bb[4], bb[5]), pk2(bb[6], bb[7]));
        *reinterpret_cast<uint2*>(fp + 8) = make_uint2(pk2(sl, 0.0f), 0u);
    }

    __syncthreads();

    // ---------- Phase 2: MFMA contraction. Wave wv: rows 4wv..4wv+3, 16 cols, 4 convs ----------
    const int lane = tid & 63;
    const int wv   = tid >> 6;
    const int r    = lane & 15;      // A row = ox_local; also B col = conv
    const int g    = lane >> 4;      // k-group

    // B fragments (col = r, k = m*32 + g*8 + e)
    const bf16x8 bb0 = *reinterpret_cast<const bf16x8*>(&Bw[r * 128 +  0 + g * 8]);
    const bf16x8 bb1 = *reinterpret_cast<const bf16x8*>(&Bw[r * 128 + 32 + g * 8]);
    const bf16x8 bb2 = *reinterpret_cast<const bf16x8*>(&Bw[r * 128 + 64 + g * 8]);
    const bf16x8 bb3 = *reinterpret_cast<const bf16x8*>(&Bw[r * 128 + 96 + g * 8]);

    // A read pointers (row-0 of wave); per-step row advance folds into offset immediates.
    const int kb0 = 8 * g, kb1 = 32 + 8 * g, kb2 = 64 + 8 * g;
    const int i0 = kb0 / 12, i1 = kb1 / 12, i2 = kb2 / 12;
    const int q0 = kb0 - 12 * i0, q1 = kb1 - 12 * i1, q2 = kb2 - 12 * i2;
    const int sbase = wv * 4 * ROWU;
    const char* fbp = (const char*)feat;
    const char* pA0 = fbp + 2 * (sbase + recIdx(i0, r) + q0);
    const char* pA1 = fbp + 2 * (sbase + recIdx(i1, r) + q1);
    const char* pAX = fbp + 2 * (sbase + recIdx(i1 + 1, r));     // row-crossing case (m1,g0)
    const char* pA2 = fbp + 2 * (sbase + recIdx(i2, r) + q2);
    const char* pA3 = fbp + 2 * (sbase + (2 * IX + r + 2) * FS); // record 8 (dy=2,dx=2)

    float* obase = out + ((size_t)((b * Cc + c) * NC) + r) * PLANE;  // valid only when r < 4

#pragma unroll
    for (int y = 0; y < 4; ++y) {
        const int oy = oy0 + wv * 4 + y;
        const int yb = y * (ROWU * 2);   // 432*y bytes
        f32x4 acc = {0.f, 0.f, 0.f, 0.f};

        // m = 0
        {
            const uint2 lo = LD2(pA0, yb), hi = LD2(pA0, yb + 8);
            acc = __builtin_amdgcn_mfma_f32_16x16x32_bf16(mkfrag(lo.x, lo.y, hi.x, hi.y), bb0, acc, 0, 0, 0);
        }
        // m = 1 (g==0 window crosses a record-row boundary -> substitute second half)
        {
            const uint2 lo = LD2(pA1, yb), hi = LD2(pA1, yb + 8);
            const uint2 xlo = LD2(pAX, yb);
            const unsigned h0 = (g == 0) ? xlo.x : hi.x;
            const unsigned h1 = (g == 0) ? xlo.y : hi.y;
            acc = __builtin_amdgcn_mfma_f32_16x16x32_bf16(mkfrag(lo.x, lo.y, h0, h1), bb1, acc, 0, 0, 0);
        }
        // m = 2
        {
            const uint2 lo = LD2(pA2, yb), hi = LD2(pA2, yb + 8);
            acc = __builtin_amdgcn_mfma_f32_16x16x32_bf16(mkfrag(lo.x, lo.y, hi.x, hi.y), bb2, acc, 0, 0, 0);
        }
        // m = 3: only k=96..107 are real (record 8); g>=1 mostly zero-padded
        {
            const uint2 q01 = LD2(pA3, yb), q23 = LD2(pA3, yb + 8), q45 = LD2(pA3, yb + 16);
            const unsigned l0 = (g == 0) ? q01.x : ((g == 1) ? q45.x : 0u);
            const unsigned l1 = (g == 0) ? q01.y : 0u;
            const unsigned h0 = (g == 0) ? q23.x : 0u;
            const unsigned h1 = (g == 0) ? q23.y : 0u;
            acc = __builtin_amdgcn_mfma_f32_16x16x32_bf16(mkfrag(l0, l1, h0, h1), bb3, acc, 0, 0, 0);
        }

        // Store: lane holds D[rows 4g..4g+3][col r]; r = conv, row = ox_local
        if (r < NC && oy < Ho) {
            const int oxs = ox0 + g * 4;
            float* op = obase + oy * Wo + oxs;
            if (oxs + 3 < Wo) {
                F4 s; s.v0 = acc[0]; s.v1 = acc[1]; s.v2 = acc[2]; s.v3 = acc[3];
                *reinterpret_cast<F4*>(op) = s;
            } else {
#pragma unroll
                for (int e = 0; e < 4; ++e)
                    if (oxs + e < Wo) op[e] = acc[e];
            }
        }
    }
}

extern "C" void kernel_launch(void* const* d_in, const int* in_sizes, int n_in,
                              void* d_out, int out_size, void* d_ws, size_t ws_size,
                              hipStream_t stream) {
    const float* x             = (const float*)d_in[0];
    const float* base_w        = (const float*)d_in[1];
    const float* spline_w      = (const float*)d_in[2];
    const float* spline_scaler = (const float*)d_in[3];
    const float* grid          = (const float*)d_in[4];
    float* out = (float*)d_out;

    const int nblocks = Bb * Cc * NYT * NXT;  // 4608
    kan_conv_kernel<<<nblocks, 256, 0, stream>>>(x, base_w, spline_w,
                                                 spline_scaler, grid, out);
}

// Round 7
// 23.970 us; speedup vs baseline: 1.0886x; 1.0886x over previous
//
#include <hip/hip_runtime.h>
#include <math.h>

// Problem constants
constexpr int Bb = 8, Cc = 16, Hh = 96, Ww = 96;
constexpr int Ho = 94, Wo = 94;          // VALID 3x3
constexpr int NC = 4;                    // n_convs
constexpr int PLANE = Ho * Wo;           // 8836

// Tiling: full-height column strip per block: 16 wide x 94 tall outputs.
// 768 blocks = exactly 3 per CU (LDS 45.5KB -> 3 blocks/CU), one dispatch round.
constexpr int TX = 16;
constexpr int IX = 18, IY = 96;          // input/feature strip (full height)
constexpr int NXT = 6;
constexpr int FS = 12;                   // bf16 per record: b0..b7, silu, 0,0,0
constexpr int ROWU = IX * FS;            // 216 ushorts per feature row
constexpr int ROWB = ROWU * 2;           // 432 bytes per feature row
// K layout: k = rec*12 + coeff, rec = dy*3+dx (0..8), K=108 padded to 128.

typedef __attribute__((ext_vector_type(4))) float f32x4;
typedef __attribute__((ext_vector_type(8))) short bf16x8;

__device__ __forceinline__ unsigned short f2bf(float f) {
    union { float f; unsigned u; } a; a.f = f;
    unsigned r = a.u + 0x7fffu + ((a.u >> 16) & 1u);   // RNE
    return (unsigned short)(r >> 16);
}
__device__ __forceinline__ unsigned pk2(float a, float b) {
    return (unsigned)f2bf(a) | ((unsigned)f2bf(b) << 16);
}
__device__ __forceinline__ bf16x8 mkfrag(unsigned a0, unsigned a1, unsigned a2, unsigned a3) {
    union { unsigned u[4]; bf16x8 v; } t;
    t.u[0] = a0; t.u[1] = a1; t.u[2] = a2; t.u[3] = a3;
    return t.v;
}
__device__ __forceinline__ int recIdx(int i, int r) {    // ushort index of record (dy,dx)=(i/3,i%3), row 0
    return ((i / 3) * IX + r + (i % 3)) * FS;
}

struct F4 { float v0, v1, v2, v3; } __attribute__((packed, aligned(4)));

#define LD2(p, off) (*reinterpret_cast<const uint2*>((const char*)(p) + (off)))

__global__ __launch_bounds__(256)
void kan_conv_kernel(const float* __restrict__ x,
                     const float* __restrict__ base_w,        // (4,9)
                     const float* __restrict__ spline_w,      // (4,9,8)
                     const float* __restrict__ spline_scaler, // (4,9)
                     const float* __restrict__ grid,          // (12)
                     float* __restrict__ out)                 // (8,64,94,94)
{
    __shared__ unsigned short feat[IY * ROWU];     // 41472 B, bf16 records
    __shared__ unsigned short Bw[16 * 128];        // 4096 B, merged weights [cv][k]

    const int tid = threadIdx.x;
    int blk = blockIdx.x;
    const int xt = blk % NXT; blk /= NXT;
    const int c  = blk % Cc;
    const int b  = blk / Cc;
    const int ox0 = xt * TX;

    // ---------- Phase 0: merged-weight B matrix -> LDS (bf16, zero-padded 16x128) ----------
    {
        const int cv = tid >> 4;          // 0..15 (only 0..3 nonzero)
        const int k0 = (tid & 15) * 8;
        unsigned d0 = 0, d1 = 0, d2 = 0, d3 = 0;
        if (cv < NC) {
            float w0=0,w1=0,w2=0,w3=0,w4=0,w5=0,w6=0,w7=0;
#pragma unroll
            for (int e = 0; e < 8; ++e) {
                const int k = k0 + e;
                float val = 0.f;
                if (k < 108) {
                    const int i  = k / 12;
                    const int cc = k - 12 * i;
                    const int wi = cv * 9 + i;
                    if (cc < 8)       val = spline_scaler[wi] * spline_w[wi * 8 + cc];
                    else if (cc == 8) val = base_w[wi];
                }
                if      (e == 0) w0 = val; else if (e == 1) w1 = val;
                else if (e == 2) w2 = val; else if (e == 3) w3 = val;
                else if (e == 4) w4 = val; else if (e == 5) w5 = val;
                else if (e == 6) w6 = val; else              w7 = val;
            }
            d0 = pk2(w0, w1); d1 = pk2(w2, w3); d2 = pk2(w4, w5); d3 = pk2(w6, w7);
        }
        *reinterpret_cast<uint4*>(&Bw[cv * 128 + k0]) = make_uint4(d0, d1, d2, d3);
    }

    // ---------- Phase 1: per-pixel features -> bf16 records in LDS (full 96x18 strip) ----------
    const float g0   = grid[0];
    const float invh = 1.0f / (grid[1] - g0);
    const float* xplane = x + (size_t)(b * Cc + c) * Hh * Ww;

    for (int p = tid; p < IX * IY; p += 256) {   // 1728 pixels, ~6.75/thread
        const int py = p / IX, px = p % IX;      // py 0..95 all in-range
        const int gx = ox0 + px;
        const float v = (gx < Ww) ? xplane[py * Ww + gx] : 0.0f;

        const float sl = v / (1.0f + __expf(-v));   // silu

        const float u = (v - g0) * invh;
        int j = (int)u;
        if (!(u >= 0.0f && u < 11.0f)) j = -100;
        const float t  = u - (float)j;
        const float t2 = t * t, t3 = t2 * t;
        const float omt = 1.0f - t;
        const float B0 = (1.0f / 6.0f) * omt * omt * omt;
        const float B1 = (1.0f / 6.0f) * (3.0f * t3 - 6.0f * t2 + 4.0f);
        const float B2 = (1.0f / 6.0f) * (-3.0f * t3 + 3.0f * t2 + 3.0f * t + 1.0f);
        const float B3 = (1.0f / 6.0f) * t3;

        float bb[8];
#pragma unroll
        for (int k = 0; k < 8; ++k) {
            float r = 0.0f;
            r = (j == k + 3) ? B0 : r;
            r = (j == k + 2) ? B1 : r;
            r = (j == k + 1) ? B2 : r;
            r = (j == k    ) ? B3 : r;
            bb[k] = r;
        }

        unsigned short* fp = &feat[p * FS];
        *reinterpret_cast<uint2*>(fp + 0) = make_uint2(pk2(bb[0], bb[1]), pk2(bb[2], bb[3]));
        *reinterpret_cast<uint2*>(fp + 4) = make_uint2(pk2(bb[4], bb[5]), pk2(bb[6], bb[7]));
        *reinterpret_cast<uint2*>(fp + 8) = make_uint2(pk2(sl, 0.0f), 0u);
    }

    __syncthreads();

    // ---------- Phase 2: MFMA contraction. Wave wv handles output rows wv+4k, k=0..23 ----------
    const int lane = tid & 63;
    const int wv   = tid >> 6;
    const int r    = lane & 15;      // A row = ox_local; also B col = conv
    const int g    = lane >> 4;      // k-group

    // B fragments (col = r, k = m*32 + g*8 + e)
    const bf16x8 bb0 = *reinterpret_cast<const bf16x8*>(&Bw[r * 128 +  0 + g * 8]);
    const bf16x8 bb1 = *reinterpret_cast<const bf16x8*>(&Bw[r * 128 + 32 + g * 8]);
    const bf16x8 bb2 = *reinterpret_cast<const bf16x8*>(&Bw[r * 128 + 64 + g * 8]);
    const bf16x8 bb3 = *reinterpret_cast<const bf16x8*>(&Bw[r * 128 + 96 + g * 8]);

    // A read pointers for this wave's row 0 (= output row wv); k*4 rows advance via offsets.
    const int kb0 = 8 * g, kb1 = 32 + 8 * g, kb2 = 64 + 8 * g;
    const int i0 = kb0 / 12, i1 = kb1 / 12, i2 = kb2 / 12;
    const int q0 = kb0 - 12 * i0, q1 = kb1 - 12 * i1, q2 = kb2 - 12 * i2;
    const char* fbp = (const char*)feat + wv * ROWB;
    const char* pA0 = fbp + 2 * (recIdx(i0, r) + q0);
    const char* pA1 = fbp + 2 * (recIdx(i1, r) + q1);
    const char* pAX = fbp + 2 * recIdx(i1 + 1, r);               // m1,g0 row-crossing case
    const char* pA2 = fbp + 2 * (recIdx(i2, r) + q2);
    const char* pA3 = fbp + 2 * ((2 * IX + r + 2) * FS);         // record 8 (dy=2,dx=2)

    float* obase = out + ((size_t)((b * Cc + c) * NC) + r) * PLANE;  // valid only when r < 4

#pragma unroll
    for (int k = 0; k < 24; ++k) {
        const int oy = wv + 4 * k;
        if (oy >= Ho) continue;          // wave-uniform (only k=23 for wv>=2)
        const int yb = k * (4 * ROWB);   // 1728*k bytes
        f32x4 acc = {0.f, 0.f, 0.f, 0.f};

        // m = 0
        {
            const uint2 lo = LD2(pA0, yb), hi = LD2(pA0, yb + 8);
            acc = __builtin_amdgcn_mfma_f32_16x16x32_bf16(mkfrag(lo.x, lo.y, hi.x, hi.y), bb0, acc, 0, 0, 0);
        }
        // m = 1 (g==0 window crosses a record-row boundary -> substitute second half)
        {
            const uint2 lo = LD2(pA1, yb), hi = LD2(pA1, yb + 8);
            const uint2 xlo = LD2(pAX, yb);
            const unsigned h0 = (g == 0) ? xlo.x : hi.x;
            const unsigned h1 = (g == 0) ? xlo.y : hi.y;
            acc = __builtin_amdgcn_mfma_f32_16x16x32_bf16(mkfrag(lo.x, lo.y, h0, h1), bb1, acc, 0, 0, 0);
        }
        // m = 2
        {
            const uint2 lo = LD2(pA2, yb), hi = LD2(pA2, yb + 8);
            acc = __builtin_amdgcn_mfma_f32_16x16x32_bf16(mkfrag(lo.x, lo.y, hi.x, hi.y), bb2, acc, 0, 0, 0);
        }
        // m = 3: only k=96..107 real (record 8)
        {
            const uint2 q01 = LD2(pA3, yb), q23 = LD2(pA3, yb + 8), q45 = LD2(pA3, yb + 16);
            const unsigned l0 = (g == 0) ? q01.x : ((g == 1) ? q45.x : 0u);
            const unsigned l1 = (g == 0) ? q01.y : 0u;
            const unsigned h0 = (g == 0) ? q23.x : 0u;
            const unsigned h1 = (g == 0) ? q23.y : 0u;
            acc = __builtin_amdgcn_mfma_f32_16x16x32_bf16(mkfrag(l0, l1, h0, h1), bb3, acc, 0, 0, 0);
        }

        // Store: lane holds D[rows 4g..4g+3][col r]; r = conv, row = ox_local
        if (r < NC) {
            const int oxs = ox0 + g * 4;
            float* op = obase + oy * Wo + oxs;
            if (oxs + 3 < Wo) {
                F4 s; s.v0 = acc[0]; s.v1 = acc[1]; s.v2 = acc[2]; s.v3 = acc[3];
                *reinterpret_cast<F4*>(op) = s;
            } else {
#pragma unroll
                for (int e = 0; e < 4; ++e)
                    if (oxs + e < Wo) op[e] = acc[e];
            }
        }
    }
}

extern "C" void kernel_launch(void* const* d_in, const int* in_sizes, int n_in,
                              void* d_out, int out_size, void* d_ws, size_t ws_size,
                              hipStream_t stream) {
    const float* x             = (const float*)d_in[0];
    const float* base_w        = (const float*)d_in[1];
    const float* spline_w      = (const float*)d_in[2];
    const float* spline_scaler = (const float*)d_in[3];
    const float* grid          = (const float*)d_in[4];
    float* out = (float*)d_out;

    const int nblocks = Bb * Cc * NXT;  // 768 = 3 per CU
    kan_conv_kernel<<<nblocks, 256, 0, stream>>>(x, base_w, spline_w,
                                                 spline_scaler, grid, out);
}

// Round 8
// 21.662 us; speedup vs baseline: 1.2046x; 1.1065x over previous
//
#include <hip/hip_runtime.h>
#include <math.h>

// Problem constants
constexpr int Bb = 8, Cc = 16, Hh = 96, Ww = 96;
constexpr int Ho = 94, Wo = 94;          // VALID 3x3
constexpr int NC = 4;                    // n_convs
constexpr int PLANE = Ho * Wo;           // 8836

// Tiling: half-height column strips: 16 wide x 47 tall outputs per block.
// LDS 25.3KB -> 6 blocks/CU (24 waves/CU, 6 waves/SIMD); 1536 blocks = 6/CU exact.
constexpr int TX = 16;
constexpr int TYS = 47;                  // output rows per strip
constexpr int IX = 18, IY = 49;          // input/feature strip
constexpr int NXT = 6, NYT = 2;
constexpr int FS = 12;                   // bf16 per record: b0..b7, silu, 0,0,0
constexpr int ROWU = IX * FS;            // 216 ushorts per feature row
constexpr int ROWB = ROWU * 2;           // 432 bytes per feature row
// K layout: k = rec*12 + coeff, rec = dy*3+dx (0..8), K=108 padded to 128.

typedef __attribute__((ext_vector_type(4))) float f32x4;
typedef __attribute__((ext_vector_type(8))) short bf16x8;

__device__ __forceinline__ unsigned short f2bf(float f) {
    union { float f; unsigned u; } a; a.f = f;
    unsigned r = a.u + 0x7fffu + ((a.u >> 16) & 1u);   // RNE
    return (unsigned short)(r >> 16);
}
__device__ __forceinline__ unsigned pk2(float a, float b) {
    return (unsigned)f2bf(a) | ((unsigned)f2bf(b) << 16);
}
__device__ __forceinline__ bf16x8 mkfrag(unsigned a0, unsigned a1, unsigned a2, unsigned a3) {
    union { unsigned u[4]; bf16x8 v; } t;
    t.u[0] = a0; t.u[1] = a1; t.u[2] = a2; t.u[3] = a3;
    return t.v;
}
__device__ __forceinline__ int recIdx(int i, int r) {    // ushort index of record (dy,dx)=(i/3,i%3), row 0
    return ((i / 3) * IX + r + (i % 3)) * FS;
}

struct F4 { float v0, v1, v2, v3; } __attribute__((packed, aligned(4)));

#define LD2(p, off) (*reinterpret_cast<const uint2*>((const char*)(p) + (off)))

__global__ __launch_bounds__(256, 6)
void kan_conv_kernel(const float* __restrict__ x,
                     const float* __restrict__ base_w,        // (4,9)
                     const float* __restrict__ spline_w,      // (4,9,8)
                     const float* __restrict__ spline_scaler, // (4,9)
                     const float* __restrict__ grid,          // (12)
                     float* __restrict__ out)                 // (8,64,94,94)
{
    __shared__ unsigned short feat[IY * ROWU];     // 21168 B, bf16 records
    __shared__ unsigned short Bw[16 * 128];        // 4096 B, merged weights [cv][k]

    const int tid = threadIdx.x;
    int blk = blockIdx.x;
    const int xt = blk % NXT; blk /= NXT;
    const int yt = blk % NYT; blk /= NYT;
    const int c  = blk % Cc;
    const int b  = blk / Cc;
    const int ox0 = xt * TX;
    const int oy0 = yt * TYS;             // 0 or 47

    // ---------- Phase 0: merged-weight B matrix -> LDS (bf16, zero-padded 16x128) ----------
    {
        const int cv = tid >> 4;          // 0..15 (only 0..3 nonzero)
        const int k0 = (tid & 15) * 8;
        unsigned d0 = 0, d1 = 0, d2 = 0, d3 = 0;
        if (cv < NC) {
            float w0=0,w1=0,w2=0,w3=0,w4=0,w5=0,w6=0,w7=0;
#pragma unroll
            for (int e = 0; e < 8; ++e) {
                const int k = k0 + e;
                float val = 0.f;
                if (k < 108) {
                    const int i  = k / 12;
                    const int cc = k - 12 * i;
                    const int wi = cv * 9 + i;
                    if (cc < 8)       val = spline_scaler[wi] * spline_w[wi * 8 + cc];
                    else if (cc == 8) val = base_w[wi];
                }
                if      (e == 0) w0 = val; else if (e == 1) w1 = val;
                else if (e == 2) w2 = val; else if (e == 3) w3 = val;
                else if (e == 4) w4 = val; else if (e == 5) w5 = val;
                else if (e == 6) w6 = val; else              w7 = val;
            }
            d0 = pk2(w0, w1); d1 = pk2(w2, w3); d2 = pk2(w4, w5); d3 = pk2(w6, w7);
        }
        *reinterpret_cast<uint4*>(&Bw[cv * 128 + k0]) = make_uint4(d0, d1, d2, d3);
    }

    // ---------- Phase 1: per-pixel features -> bf16 records in LDS (49x18 strip) ----------
    const float g0   = grid[0];
    const float invh = 1.0f / (grid[1] - g0);
    const float* xplane = x + (size_t)(b * Cc + c) * Hh * Ww;

    for (int p = tid; p < IX * IY; p += 256) {   // 882 pixels, ~3.45/thread
        const int py = p / IX, px = p % IX;
        const int gy = oy0 + py;                 // <= 47+48 = 95, always in range
        const int gx = ox0 + px;
        const float v = (gx < Ww) ? xplane[gy * Ww + gx] : 0.0f;

        const float sl = v / (1.0f + __expf(-v));   // silu

        const float u = (v - g0) * invh;
        int j = (int)u;
        if (!(u >= 0.0f && u < 11.0f)) j = -100;
        const float t  = u - (float)j;
        const float t2 = t * t, t3 = t2 * t;
        const float omt = 1.0f - t;
        const float B0 = (1.0f / 6.0f) * omt * omt * omt;
        const float B1 = (1.0f / 6.0f) * (3.0f * t3 - 6.0f * t2 + 4.0f);
        const float B2 = (1.0f / 6.0f) * (-3.0f * t3 + 3.0f * t2 + 3.0f * t + 1.0f);
        const float B3 = (1.0f / 6.0f) * t3;

        float bb[8];
#pragma unroll
        for (int k = 0; k < 8; ++k) {
            float r = 0.0f;
            r = (j == k + 3) ? B0 : r;
            r = (j == k + 2) ? B1 : r;
            r = (j == k + 1) ? B2 : r;
            r = (j == k    ) ? B3 : r;
            bb[k] = r;
        }

        unsigned short* fp = &feat[p * FS];
        *reinterpret_cast<uint2*>(fp + 0) = make_uint2(pk2(bb[0], bb[1]), pk2(bb[2], bb[3]));
        *reinterpret_cast<uint2*>(fp + 4) = make_uint2(pk2(bb[4], bb[5]), pk2(bb[6], bb[7]));
        *reinterpret_cast<uint2*>(fp + 8) = make_uint2(pk2(sl, 0.0f), 0u);
    }

    __syncthreads();

    // ---------- Phase 2: MFMA contraction. Wave wv handles local rows wv+4k, k=0..11 ----------
    const int lane = tid & 63;
    const int wv   = tid >> 6;
    const int r    = lane & 15;      // A row = ox_local; also B col = conv
    const int g    = lane >> 4;      // k-group

    // B fragments (col = r, k = m*32 + g*8 + e)
    const bf16x8 bb0 = *reinterpret_cast<const bf16x8*>(&Bw[r * 128 +  0 + g * 8]);
    const bf16x8 bb1 = *reinterpret_cast<const bf16x8*>(&Bw[r * 128 + 32 + g * 8]);
    const bf16x8 bb2 = *reinterpret_cast<const bf16x8*>(&Bw[r * 128 + 64 + g * 8]);
    const bf16x8 bb3 = *reinterpret_cast<const bf16x8*>(&Bw[r * 128 + 96 + g * 8]);

    // A read pointers for this wave's local row 0 (= local output row wv).
    const int kb0 = 8 * g, kb1 = 32 + 8 * g, kb2 = 64 + 8 * g;
    const int i0 = kb0 / 12, i1 = kb1 / 12, i2 = kb2 / 12;
    const int q0 = kb0 - 12 * i0, q1 = kb1 - 12 * i1, q2 = kb2 - 12 * i2;
    const char* fbp = (const char*)feat + wv * ROWB;
    const char* pA0 = fbp + 2 * (recIdx(i0, r) + q0);
    const char* pA1 = fbp + 2 * (recIdx(i1, r) + q1);
    const char* pAX = fbp + 2 * recIdx(i1 + 1, r);               // m1,g0 row-crossing case
    const char* pA2 = fbp + 2 * (recIdx(i2, r) + q2);
    const char* pA3 = fbp + 2 * ((2 * IX + r + 2) * FS);         // record 8 (dy=2,dx=2)

    float* obase = out + ((size_t)((b * Cc + c) * NC) + r) * PLANE;  // valid only when r < 4

#pragma unroll
    for (int k = 0; k < 12; ++k) {
        const int oyl = wv + 4 * k;      // local output row
        if (oyl >= TYS) continue;        // wave-uniform (only k=11, wv>=3)
        const int yb = k * (4 * ROWB);
        f32x4 acc = {0.f, 0.f, 0.f, 0.f};

        // m = 0
        {
            const uint2 lo = LD2(pA0, yb), hi = LD2(pA0, yb + 8);
            acc = __builtin_amdgcn_mfma_f32_16x16x32_bf16(mkfrag(lo.x, lo.y, hi.x, hi.y), bb0, acc, 0, 0, 0);
        }
        // m = 1 (g==0 window crosses a record-row boundary -> substitute second half)
        {
            const uint2 lo = LD2(pA1, yb), hi = LD2(pA1, yb + 8);
            const uint2 xlo = LD2(pAX, yb);
            const unsigned h0 = (g == 0) ? xlo.x : hi.x;
            const unsigned h1 = (g == 0) ? xlo.y : hi.y;
            acc = __builtin_amdgcn_mfma_f32_16x16x32_bf16(mkfrag(lo.x, lo.y, h0, h1), bb1, acc, 0, 0, 0);
        }
        // m = 2
        {
            const uint2 lo = LD2(pA2, yb), hi = LD2(pA2, yb + 8);
            acc = __builtin_amdgcn_mfma_f32_16x16x32_bf16(mkfrag(lo.x, lo.y, hi.x, hi.y), bb2, acc, 0, 0, 0);
        }
        // m = 3: only k=96..107 real (record 8)
        {
            const uint2 q01 = LD2(pA3, yb), q23 = LD2(pA3, yb + 8), q45 = LD2(pA3, yb + 16);
            const unsigned l0 = (g == 0) ? q01.x : ((g == 1) ? q45.x : 0u);
            const unsigned l1 = (g == 0) ? q01.y : 0u;
            const unsigned h0 = (g == 0) ? q23.x : 0u;
            const unsigned h1 = (g == 0) ? q23.y : 0u;
            acc = __builtin_amdgcn_mfma_f32_16x16x32_bf16(mkfrag(l0, l1, h0, h1), bb3, acc, 0, 0, 0);
        }

        // Store: lane holds D[rows 4g..4g+3][col r]; r = conv, row = ox_local
        if (r < NC) {
            const int oy = oy0 + oyl;    // < 94 by construction
            const int oxs = ox0 + g * 4;
            float* op = obase + oy * Wo + oxs;
            if (oxs + 3 < Wo) {
                F4 s; s.v0 = acc[0]; s.v1 = acc[1]; s.v2 = acc[2]; s.v3 = acc[3];
                *reinterpret_cast<F4*>(op) = s;
            } else {
#pragma unroll
                for (int e = 0; e < 4; ++e)
                    if (oxs + e < Wo) op[e] = acc[e];
            }
        }
    }
}

extern "C" void kernel_launch(void* const* d_in, const int* in_sizes, int n_in,
                              void* d_out, int out_size, void* d_ws, size_t ws_size,
                              hipStream_t stream) {
    const float* x             = (const float*)d_in[0];
    const float* base_w        = (const float*)d_in[1];
    const float* spline_w      = (const float*)d_in[2];
    const float* spline_scaler = (const float*)d_in[3];
    const float* grid          = (const float*)d_in[4];
    float* out = (float*)d_out;

    const int nblocks = Bb * Cc * NXT * NYT;  // 1536 = 6 per CU
    kan_conv_kernel<<<nblocks, 256, 0, stream>>>(x, base_w, spline_w,
                                                 spline_scaler, grid, out);
}

// Round 10
// 20.041 us; speedup vs baseline: 1.3020x; 1.0809x over previous
//
#include <hip/hip_runtime.h>
#include <math.h>

// Problem constants
constexpr int Bb = 8, Cc = 16, Hh = 96, Ww = 96;
constexpr int Ho = 94, Wo = 94;          // VALID 3x3
constexpr int NC = 4;                    // n_convs
constexpr int PLANE = Ho * Wo;           // 8836

// Tiling: 16 wide x 47 out-rows per block; 1536 blocks = 6/CU (LDS ~24KB).
constexpr int TX = 16, TYS = 47;
constexpr int IX = 18, IY = 49;          // input/feature strip
constexpr int NXT = 6, NYT = 2;
constexpr int FS = 12;                   // ushorts per record: b0..b7, silu, 0,0,0
constexpr int ROWU = IX * FS;            // 216
constexpr int ROWB = ROWU * 2;           // 432 B
constexpr int BWS = 72;                  // Bw row stride (ushorts) - bank spread
// Stage-1 K layout (window r = ushorts [12r,12r+36)): k=12*j+o, j=dx, o=feat.
// B col = 4*d + cv (d=dy). K padded to 64 over 2 MFMAs; pads hit zero B weights.

typedef __attribute__((ext_vector_type(4))) float f32x4;
typedef __attribute__((ext_vector_type(8))) short bf16x8;

template <int N> struct IC { static constexpr int value = N; };

__device__ __forceinline__ unsigned short f2bf(float f) {
    union { float f; unsigned u; } a; a.f = f;
    unsigned r = a.u + 0x7fffu + ((a.u >> 16) & 1u);   // RNE
    return (unsigned short)(r >> 16);
}
__device__ __forceinline__ unsigned pk2(float a, float b) {
    return (unsigned)f2bf(a) | ((unsigned)f2bf(b) << 16);
}
__device__ __forceinline__ bf16x8 mkfrag(unsigned a0, unsigned a1, unsigned a2, unsigned a3) {
    union { unsigned u[4]; bf16x8 v; } t;
    t.u[0] = a0; t.u[1] = a1; t.u[2] = a2; t.u[3] = a3;
    return t.v;
}
// lane i <- lane i-4 / i-8 within each 16-lane row (row_shr; rocPRIM scan convention)
__device__ __forceinline__ float dpp_shr4(float v) {
    return __int_as_float(__builtin_amdgcn_update_dpp(0, __float_as_int(v), 0x114, 0xF, 0xF, true));
}
__device__ __forceinline__ float dpp_shr8(float v) {
    return __int_as_float(__builtin_amdgcn_update_dpp(0, __float_as_int(v), 0x118, 0xF, 0xF, true));
}

struct F4 { float v0, v1, v2, v3; } __attribute__((packed, aligned(4)));

__global__ __launch_bounds__(256, 6)
void kan_conv_kernel(const float* __restrict__ x,
                     const float* __restrict__ base_w,        // (4,9)
                     const float* __restrict__ spline_w,      // (4,9,8)
                     const float* __restrict__ spline_scaler, // (4,9)
                     const float* __restrict__ grid,          // (12)
                     float* __restrict__ out)                 // (8,64,94,94)
{
    __shared__ unsigned short feat[IY * ROWU + 256];  // +512B zeroed pad for overreads
    __shared__ unsigned short Bw[16 * BWS];

    const int tid = threadIdx.x;
    int blk = blockIdx.x;
    const int xt = blk % NXT; blk /= NXT;
    const int yt = blk % NYT; blk /= NYT;
    const int c  = blk % Cc;
    const int b  = blk / Cc;
    const int ox0 = xt * TX;
    const int oy0 = yt * TYS;

    // ---------- Phase 0: merged d-packed weights -> LDS; zero feat pad ----------
    {
        const int col = tid >> 4;         // 0..15 = 4*d + cv (12 used)
        const int k0  = (tid & 15) * 4;   // 4 k-slots per thread (k 0..63)
        const int d = col >> 2, cv = col & 3;
        unsigned short w[4];
#pragma unroll
        for (int e = 0; e < 4; ++e) {
            const int k = k0 + e;
            float val = 0.f;
            if (col < 12 && k < 36) {
                const int j = k / 12, o = k - 12 * j;     // j=dx, o=feat
                const int wi = cv * 9 + 3 * d + j;
                if (o < 8)       val = spline_scaler[wi] * spline_w[wi * 8 + o];
                else if (o == 8) val = base_w[wi];
            }
            w[e] = f2bf(val);
        }
        *reinterpret_cast<uint2*>(&Bw[col * BWS + k0]) =
            make_uint2((unsigned)w[0] | ((unsigned)w[1] << 16),
                       (unsigned)w[2] | ((unsigned)w[3] << 16));
        feat[IY * ROWU + tid] = 0;        // zero pad region (MFMA garbage hazard)
    }

    // ---------- Phase 1: per-pixel features -> bf16 records in LDS ----------
    const float g0   = grid[0];
    const float invh = 1.0f / (grid[1] - g0);
    const float* xplane = x + (size_t)(b * Cc + c) * Hh * Ww;

    for (int p = tid; p < IX * IY; p += 256) {   // 882 records
        const int py = p / IX, px = p % IX;
        const int gy = oy0 + py;                 // <= 95
        const int gx = ox0 + px;
        const float v = (gx < Ww) ? xplane[gy * Ww + gx] : 0.0f;

        const float sl = v / (1.0f + __expf(-v));   // silu

        const float u = (v - g0) * invh;
        int j = (int)u;
        if (!(u >= 0.0f && u < 11.0f)) j = -100;
        const float t  = u - (float)j;
        const float t2 = t * t, t3 = t2 * t;
        const float omt = 1.0f - t;
        const float B0 = (1.0f / 6.0f) * omt * omt * omt;
        const float B1 = (1.0f / 6.0f) * (3.0f * t3 - 6.0f * t2 + 4.0f);
        const float B2 = (1.0f / 6.0f) * (-3.0f * t3 + 3.0f * t2 + 3.0f * t + 1.0f);
        const float B3 = (1.0f / 6.0f) * t3;

        float bb[8];
#pragma unroll
        for (int k = 0; k < 8; ++k) {
            float r = 0.0f;
            r = (j == k + 3) ? B0 : r;
            r = (j == k + 2) ? B1 : r;
            r = (j == k + 1) ? B2 : r;
            r = (j == k    ) ? B3 : r;
            bb[k] = r;
        }

        unsigned short* fp = &feat[p * FS];
        *reinterpret_cast<uint2*>(fp + 0) = make_uint2(pk2(bb[0], bb[1]), pk2(bb[2], bb[3]));
        *reinterpret_cast<uint2*>(fp + 4) = make_uint2(pk2(bb[4], bb[5]), pk2(bb[6], bb[7]));
        *reinterpret_cast<uint2*>(fp + 8) = make_uint2(pk2(sl, 0.0f), 0u);
    }

    __syncthreads();

    // ---------- Phase 2: sliding-dy MFMA. Wave wv: out rows 12wv..12wv+11 (local) ----------
    const int lane = tid & 63;
    const int wv   = tid >> 6;
    const int r    = lane & 15;      // A row (pixel window) / B col (4d+cv)
    const int g    = lane >> 4;      // k-group

    const bf16x8 wb1 = *reinterpret_cast<const bf16x8*>(&Bw[r * BWS +  0 + 8 * g]);
    const bf16x8 wb2 = *reinterpret_cast<const bf16x8*>(&Bw[r * BWS + 32 + 8 * g]);

    // A base: input local row 12wv, window r, k-group g.
    const char* fb = (const char*)feat + (12 * wv) * ROWB + 24 * r + 16 * g;

    const int cvl = r & 3;
    float* obase = out + ((size_t)((b * Cc + c) * NC) + cvl) * PLANE;  // used when r in [8,12)
    const bool storer = (r >= 8) && (r < 12);
    const int oxs = ox0 + 4 * g;
    const bool fullstore = (oxs + 3 < Wo);

    f32x4 sA, sB, sC;
    const f32x4 zz = {0.f, 0.f, 0.f, 0.f};
    sA = zz; sB = zz; sC = zz;

    auto kstep = [&](auto ITC, f32x4& cur, f32x4& p1, f32x4& p2) {
        constexpr int IT = decltype(ITC)::value;
        const uint2 lo = *reinterpret_cast<const uint2*>(fb + IT * ROWB);
        const uint2 hi = *reinterpret_cast<const uint2*>(fb + IT * ROWB + 8);
        const uint2 x2 = *reinterpret_cast<const uint2*>(fb + IT * ROWB + 64);
        cur = __builtin_amdgcn_mfma_f32_16x16x32_bf16(mkfrag(lo.x, lo.y, hi.x, hi.y), wb1, zz, 0, 0, 0);
        cur = __builtin_amdgcn_mfma_f32_16x16x32_bf16(mkfrag(x2.x, x2.y, x2.x, x2.y), wb2, cur, 0, 0, 0);
        if constexpr (IT >= 2) {
            const int lrow = 12 * wv + IT - 2;
            if (lrow < TYS) {                      // wave-uniform
                f32x4 tot;
                // col 8+cv (d=2, cur) + col 4+cv (d=1, prev step) + col cv (d=0, prev2)
                tot[0] = cur[0] + dpp_shr4(p1[0]) + dpp_shr8(p2[0]);
                tot[1] = cur[1] + dpp_shr4(p1[1]) + dpp_shr8(p2[1]);
                tot[2] = cur[2] + dpp_shr4(p1[2]) + dpp_shr8(p2[2]);
                tot[3] = cur[3] + dpp_shr4(p1[3]) + dpp_shr8(p2[3]);
                if (storer) {
                    const int oy = oy0 + lrow;
                    float* op = obase + oy * Wo + oxs;
                    if (fullstore) {
                        F4 s; s.v0 = tot[0]; s.v1 = tot[1]; s.v2 = tot[2]; s.v3 = tot[3];
                        *reinterpret_cast<F4*>(op) = s;
                    } else {
#pragma unroll
                        for (int e = 0; e < 4; ++e)
                            if (oxs + e < Wo) op[e] = tot[e];
                    }
                }
            }
        }
    };

    kstep(IC<0>{},  sA, sC, sB);
    kstep(IC<1>{},  sB, sA, sC);
    kstep(IC<2>{},  sC, sB, sA);
    kstep(IC<3>{},  sA, sC, sB);
    kstep(IC<4>{},  sB, sA, sC);
    kstep(IC<5>{},  sC, sB, sA);
    kstep(IC<6>{},  sA, sC, sB);
    kstep(IC<7>{},  sB, sA, sC);
    kstep(IC<8>{},  sC, sB, sA);
    kstep(IC<9>{},  sA, sC, sB);
    kstep(IC<10>{}, sB, sA, sC);
    kstep(IC<11>{}, sC, sB, sA);
    kstep(IC<12>{}, sA, sC, sB);
    kstep(IC<13>{}, sB, sA, sC);
}

extern "C" void kernel_launch(void* const* d_in, const int* in_sizes, int n_in,
                              void* d_out, int out_size, void* d_ws, size_t ws_size,
                              hipStream_t stream) {
    const float* x             = (const float*)d_in[0];
    const float* base_w        = (const float*)d_in[1];
    const float* spline_w      = (const float*)d_in[2];
    const float* spline_scaler = (const float*)d_in[3];
    const float* grid          = (const float*)d_in[4];
    float* out = (float*)d_out;

    const int nblocks = Bb * Cc * NXT * NYT;  // 1536 = 6 per CU
    kan_conv_kernel<<<nblocks, 256, 0, stream>>>(x, base_w, spline_w,
                                                 spline_scaler, grid, out);
}